// Round 10
// baseline (334.070 us; speedup 1.0000x reference)
//
#include <hip/hip_runtime.h>
#include <hip/hip_bf16.h>

typedef __attribute__((ext_vector_type(8))) __bf16 bf16x8;
typedef __attribute__((ext_vector_type(4))) float  f32x4;

#define T_SEQ 256
#define F_IN  18
#define HID   64
#define NB    16
#define NO    15

static __device__ __forceinline__ float rcp_fast(float x) {
    return __builtin_amdgcn_rcpf(x);
}
static __device__ __forceinline__ float sigm(float x) {
    return rcp_fast(1.0f + __expf(-x));
}
static __device__ __forceinline__ float tanh_fast(float x) {
    // 1 - 2/(e^{2x}+1); saturates correctly for |x| large
    return 1.0f - 2.0f * rcp_fast(__expf(2.0f * x) + 1.0f);
}

// 256 blocks x 1024 threads (16 waves). Block owns 16 batches; wave w owns
// gate-row tile T=w (permuted rows p=4u+g -> units u=4w..4w+3).
// Lane: bb=l&15 (batch/col), q=l>>4 (k-group). C layout: col=bb, row=4q+r
// -> u=4w+q, gate g=r. Lane-local cell update.
//
// LDS layout: [part][k-chunk][bb][idx] -- element linear index =
// chunk*128 + bb*8 + idx. Lane l=16q+bb needs k=8q+r (chunk=q, idx=r)
// -> ELEMENT offset 128q+8bb = 8*l  (R9 bug: used 16*l = byte offset as
// element offset -> OOB reads -> NaN). Wave reads contiguous 1024B,
// zero read bank conflicts.
//
// K-packing (split-precision 3-product; A/B segment maps must agree):
//   input proj (K=64, 2 MFMAs):
//     A = [Wih_hi(18) | Wih_lo(18) | Wih_hi(18) | 0..]
//     B = [x_hi(18)   | x_hi(18)   | x_lo(18)   | 0..]
//   recurrent (6 MFMAs): Whi.hhi + Wlo.hhi + Whi.hlo
// MFMA split into 2 independent 4-chains (acc_a/acc_b), summed before
// gate math.
__global__ __launch_bounds__(1024, 4) void lstm_fused(
    const float* __restrict__ X,
    const float* __restrict__ Wih,
    const float* __restrict__ Whh,
    const float* __restrict__ bih,
    const float* __restrict__ bhh,
    const float* __restrict__ Wcls,
    const float* __restrict__ bcls,
    float* __restrict__ out)
{
    const int tid = threadIdx.x;
    const int l   = tid & 63;
    const int w   = tid >> 6;   // wave id = row-tile
    const int q   = l >> 4;     // k-group
    const int bb  = l & 15;     // batch within block
    const int b0  = blockIdx.x * NB;

    // [dbuf][part hi/lo][k-chunk][bb][idx]
    __shared__ __align__(16) __bf16 hbuf[2][2][8][NB][8];
    // [dbuf][k-chunk][bb][idx]; packed k = [x_hi(18)|x_hi(18)|x_lo(18)|0..]
    __shared__ __align__(16) __bf16 xbuf[2][8][NB][8];
    __shared__ float h32[NB][HID];

    // ---- x staging map: thread tid stages element linear-index tid ----
    // tid bits = [chunk(3)][bb(4)][idx(3)] -> linear == tid; ds_write of
    // consecutive tids is contiguous 2B (conflict-free).
    const int sb = (tid >> 3) & 15;                    // batch
    const int sk = ((tid >> 7) << 3) | (tid & 7);      // packed k
    int f_s, part_s;                                   // 0=hi, 1=lo, 2=zero
    if (sk < 18)      { f_s = sk;      part_s = 0; }
    else if (sk < 36) { f_s = sk - 18; part_s = 0; }
    else if (sk < 54) { f_s = sk - 36; part_s = 1; }
    else              { f_s = 0;       part_s = 2; }
    const float* xsrc = X + ((long)(b0 + sb) * T_SEQ) * F_IN + f_s;
    __bf16* const xbase = &xbuf[0][0][0][0];           // + dbuf*1024 + tid

    // ---- zero initial h (t=0 reads hbuf[0]; hbuf[1] fully written at t=0) ----
    {
        __bf16* hz = &hbuf[0][0][0][0][0];
        for (int i = tid; i < 2 * 8 * NB * 8; i += 1024) hz[i] = (__bf16)0.0f;
    }
    // ---- stage x for t=0 ----
    {
        const float v = (part_s == 2) ? 0.0f : xsrc[0];
        const __bf16 hi = (__bf16)v;
        xbase[tid] = (part_s == 1) ? (__bf16)(v - (float)hi) : hi;
    }

    // ---- constant A-fragments (live whole kernel) ----
    bf16x8 whh_hi[2], whh_lo[2], wih[2];
    {
        const int prow = 16 * w + bb;                   // permuted gate row
        const int jrow = (prow & 3) * 64 + (prow >> 2); // original row g*64+u
#pragma unroll
        for (int kk = 0; kk < 2; ++kk) {
            bf16x8 hi, lo, xa;
#pragma unroll
            for (int r = 0; r < 8; ++r) {
                const int k = 32 * kk + 8 * q + r;
                const float v = Whh[jrow * HID + k];
                const __bf16 vh = (__bf16)v;
                hi[r] = vh;
                lo[r] = (__bf16)(v - (float)vh);
                int f, part;
                if (k < 18)      { f = k;      part = 0; }
                else if (k < 36) { f = k - 18; part = 1; }
                else if (k < 54) { f = k - 36; part = 0; }
                else             { f = 0;      part = 2; }
                const float wv = (part == 2) ? 0.0f : Wih[jrow * F_IN + f];
                const __bf16 wh = (__bf16)wv;
                xa[r] = (part == 1) ? (__bf16)(wv - (float)wh) : wh;
            }
            whh_hi[kk] = hi;
            whh_lo[kk] = lo;
            wih[kk]    = xa;
        }
    }

    const int u_c = 4 * w + q;                    // this lane's hidden unit
    float bias4[4];
#pragma unroll
    for (int r = 0; r < 4; ++r) bias4[r] = bih[r * 64 + u_c] + bhh[r * 64 + u_c];

    // precomputed LDS pointers (ELEMENT offsets; dbuf stride: hbuf 2048, xbuf 1024)
    __bf16* const hw_base = &hbuf[0][0][0][0][0] +
                            ((u_c >> 3) * 128 + bb * 8 + (u_c & 7)); // +part*1024
    const __bf16* const hr_base = &hbuf[0][0][0][0][0] + 8 * (size_t)l; // part0 chunk q
    const __bf16* const xr_base = &xbuf[0][0][0][0] + 8 * (size_t)l;

    __syncthreads();

    float cst = 0.0f;

#pragma unroll 2
    for (int t = 0; t < T_SEQ; ++t) {
        const int cur = t & 1;
        const int nxt = cur ^ 1;

        // issue next-step x load early (hides under MFMA chain)
        const int tn = (t + 1 < T_SEQ) ? (t + 1) : (T_SEQ - 1);
        const float vstage = (part_s == 2) ? 0.0f : xsrc[tn * F_IN];

        // B-fragments: lane l reads contiguous 16B at element 8*l -- conflict-free
        const __bf16* hr = hr_base + cur * 2048;
        const __bf16* xr = xr_base + cur * 1024;
        const bf16x8 bx0 = *reinterpret_cast<const bf16x8*>(xr);          // chunks 0-3
        const bf16x8 bx1 = *reinterpret_cast<const bf16x8*>(xr + 512);    // chunks 4-7
        const bf16x8 bh0 = *reinterpret_cast<const bf16x8*>(hr);          // hi, 0-3
        const bf16x8 bh1 = *reinterpret_cast<const bf16x8*>(hr + 512);    // hi, 4-7
        const bf16x8 bl0 = *reinterpret_cast<const bf16x8*>(hr + 1024);   // lo, 0-3
        const bf16x8 bl1 = *reinterpret_cast<const bf16x8*>(hr + 1536);   // lo, 4-7

        // two independent 4-deep MFMA chains
        f32x4 acc_a = {bias4[0], bias4[1], bias4[2], bias4[3]};
        f32x4 acc_b = {0.0f, 0.0f, 0.0f, 0.0f};
        acc_a = __builtin_amdgcn_mfma_f32_16x16x32_bf16(wih[0],    bx0, acc_a, 0, 0, 0);
        acc_b = __builtin_amdgcn_mfma_f32_16x16x32_bf16(wih[1],    bx1, acc_b, 0, 0, 0);
        acc_a = __builtin_amdgcn_mfma_f32_16x16x32_bf16(whh_hi[0], bh0, acc_a, 0, 0, 0);
        acc_b = __builtin_amdgcn_mfma_f32_16x16x32_bf16(whh_hi[1], bh1, acc_b, 0, 0, 0);
        acc_a = __builtin_amdgcn_mfma_f32_16x16x32_bf16(whh_lo[0], bh0, acc_a, 0, 0, 0);
        acc_b = __builtin_amdgcn_mfma_f32_16x16x32_bf16(whh_lo[1], bh1, acc_b, 0, 0, 0);
        acc_a = __builtin_amdgcn_mfma_f32_16x16x32_bf16(whh_hi[0], bl0, acc_a, 0, 0, 0);
        acc_b = __builtin_amdgcn_mfma_f32_16x16x32_bf16(whh_hi[1], bl1, acc_b, 0, 0, 0);

        // write next-step x into the other buffer (contiguous 2B per tid)
        {
            const __bf16 sh = (__bf16)vstage;
            xbase[nxt * 1024 + tid] = (part_s == 1) ? (__bf16)(vstage - (float)sh) : sh;
        }

        const f32x4 acc = acc_a + acc_b;

        // lane-local cell update: acc[r] = gate {i,f,g,o} of (bb, u_c)
        const float gi = sigm(acc[0]);
        const float gf = sigm(acc[1]);
        const float gg = tanh_fast(acc[2]);
        const float go = sigm(acc[3]);
        const float c  = gf * cst + gi * gg;
        cst = c;
        const float h  = go * tanh_fast(c);
        const __bf16 hh = (__bf16)h;
        const __bf16 hl = (__bf16)(h - (float)hh);
        __bf16* hw = hw_base + nxt * 2048;
        hw[0]    = hh;
        hw[1024] = hl;
        if (t == T_SEQ - 1) h32[bb][u_c] = h;

        __syncthreads();
    }

    // ---- classifier epilogue: out[b][o] = h . Wcls[o] + bcls[o] ----
    if (tid < NB * NO) {
        const int bo = tid / NO;
        const int o  = tid % NO;
        float s = bcls[o];
#pragma unroll 8
        for (int k = 0; k < HID; ++k)
            s += h32[bo][k] * Wcls[o * HID + k];
        out[(long)(b0 + bo) * NO + o] = s;
    }
}

extern "C" void kernel_launch(void* const* d_in, const int* in_sizes, int n_in,
                              void* d_out, int out_size, void* d_ws, size_t ws_size,
                              hipStream_t stream)
{
    const float* X    = (const float*)d_in[0];
    const float* Wih  = (const float*)d_in[1];
    const float* Whh  = (const float*)d_in[2];
    const float* bih  = (const float*)d_in[3];
    const float* bhh  = (const float*)d_in[4];
    const float* Wcls = (const float*)d_in[5];
    const float* bcls = (const float*)d_in[6];
    float* outp = (float*)d_out;

    dim3 grid(4096 / NB);   // 256 blocks -> 1 per CU
    dim3 block(1024);       // 16 waves -> 4 waves/SIMD
    lstm_fused<<<grid, block, 0, stream>>>(X, Wih, Whh, bih, bhh, Wcls, bcls, outp);
}

// Round 11
// 282.796 us; speedup vs baseline: 1.1813x; 1.1813x over previous
//
#include <hip/hip_runtime.h>
#include <hip/hip_bf16.h>

typedef __attribute__((ext_vector_type(8))) __bf16 bf16x8;
typedef __attribute__((ext_vector_type(4))) float  f32x4;

#define T_SEQ 256
#define F_IN  18
#define HID   64
#define NB    16
#define NO    15

static __device__ __forceinline__ float rcp_fast(float x) {
    return __builtin_amdgcn_rcpf(x);
}
static __device__ __forceinline__ float sigm(float x) {
    return rcp_fast(1.0f + __expf(-x));
}
static __device__ __forceinline__ float tanh_fast(float x) {
    // 1 - 2/(e^{2x}+1); saturates correctly for |x| large
    return 1.0f - 2.0f * rcp_fast(__expf(2.0f * x) + 1.0f);
}

// Barrier WITHOUT the compiler's vmcnt(0) drain: only LDS ordering is needed
// across steps (h/x staging buffers). Thread-private global prefetch loads
// legitimately stay in flight across it (T4 counted-wait principle; the
// compiler waits vmcnt at the actual register use). "memory" clobber keeps
// ds ops ordered around it; lgkmcnt(0)+s_barrier fused in one asm so nothing
// can be scheduled between them.
#define BARRIER_LDS() asm volatile("s_waitcnt lgkmcnt(0)\n\ts_barrier" ::: "memory")

// 256 blocks x 1024 threads (16 waves). Block owns 16 batches; wave w owns
// gate-row tile T=w (permuted rows p=4u+g -> units u=4w..4w+3).
// Lane: bb=l&15 (batch/col), q=l>>4 (k-group). C layout: col=bb, row=4q+r
// -> u=4w+q, gate g=r. Lane-local cell update.
//
// LDS layout: [part][k-chunk][bb][idx], element linear = chunk*128+bb*8+idx.
// Lane l reads its 16B B-fragment at ELEMENT offset 8*l (contiguous 1024B
// per wave, zero read conflicts).
//
// K-packing (split-precision 3-product; A/B segment maps must agree):
//   input proj: A=[Wih_hi(18)|Wih_lo(18)|Wih_hi(18)|0..]
//               B=[x_hi(18)  |x_hi(18)  |x_lo(18)  |0..]
//   recurrent:  Whi.hhi + Wlo.hhi + Whi.hlo
// 8 MFMAs as 4 independent 2-deep chains (a..d), summed before gate math.
//
// X path (R11): 4-deep per-thread prefetch queue xq[] -- at step t consume
// x(t+1), issue load of x(t+5). Combined with BARRIER_LDS (no vmcnt drain),
// HBM latency (~900cyc) is covered by ~4 steps of compute.
__global__ __launch_bounds__(1024, 4) void lstm_fused(
    const float* __restrict__ X,
    const float* __restrict__ Wih,
    const float* __restrict__ Whh,
    const float* __restrict__ bih,
    const float* __restrict__ bhh,
    const float* __restrict__ Wcls,
    const float* __restrict__ bcls,
    float* __restrict__ out)
{
    const int tid = threadIdx.x;
    const int l   = tid & 63;
    const int w   = tid >> 6;   // wave id = row-tile
    const int q   = l >> 4;     // k-group
    const int bb  = l & 15;     // batch within block
    const int b0  = blockIdx.x * NB;

    // [dbuf][part hi/lo][k-chunk][bb][idx]
    __shared__ __align__(16) __bf16 hbuf[2][2][8][NB][8];
    // [dbuf][k-chunk][bb][idx]; packed k = [x_hi(18)|x_hi(18)|x_lo(18)|0..]
    __shared__ __align__(16) __bf16 xbuf[2][8][NB][8];
    __shared__ float h32[NB][HID];

    // ---- x staging map: thread tid stages element linear-index tid ----
    const int sb = (tid >> 3) & 15;                    // batch
    const int sk = ((tid >> 7) << 3) | (tid & 7);      // packed k
    int f_s, part_s;                                   // 0=hi, 1=lo, 2=zero
    if (sk < 18)      { f_s = sk;      part_s = 0; }
    else if (sk < 36) { f_s = sk - 18; part_s = 0; }
    else if (sk < 54) { f_s = sk - 36; part_s = 1; }
    else              { f_s = 0;       part_s = 2; }
    const float* xsrc = X + ((long)(b0 + sb) * T_SEQ) * F_IN + f_s;
    __bf16* const xbase = &xbuf[0][0][0][0];           // + dbuf*1024 + tid

    // ---- zero initial h ----
    {
        __bf16* hz = &hbuf[0][0][0][0][0];
        for (int i = tid; i < 2 * 8 * NB * 8; i += 1024) hz[i] = (__bf16)0.0f;
    }
    // ---- stage x for t=0; prefetch queue for x(1..4) ----
    {
        const float v = (part_s == 2) ? 0.0f : xsrc[0];
        const __bf16 hi = (__bf16)v;
        xbase[tid] = (part_s == 1) ? (__bf16)(v - (float)hi) : hi;
    }
    float xq[4];
#pragma unroll
    for (int i = 0; i < 4; ++i)
        xq[i] = (part_s == 2) ? 0.0f : xsrc[(1 + i) * F_IN];

    // ---- constant A-fragments (live whole kernel) ----
    bf16x8 whh_hi[2], whh_lo[2], wih[2];
    {
        const int prow = 16 * w + bb;                   // permuted gate row
        const int jrow = (prow & 3) * 64 + (prow >> 2); // original row g*64+u
#pragma unroll
        for (int kk = 0; kk < 2; ++kk) {
            bf16x8 hi, lo, xa;
#pragma unroll
            for (int r = 0; r < 8; ++r) {
                const int k = 32 * kk + 8 * q + r;
                const float v = Whh[jrow * HID + k];
                const __bf16 vh = (__bf16)v;
                hi[r] = vh;
                lo[r] = (__bf16)(v - (float)vh);
                int f, part;
                if (k < 18)      { f = k;      part = 0; }
                else if (k < 36) { f = k - 18; part = 1; }
                else if (k < 54) { f = k - 36; part = 0; }
                else             { f = 0;      part = 2; }
                const float wv = (part == 2) ? 0.0f : Wih[jrow * F_IN + f];
                const __bf16 wh = (__bf16)wv;
                xa[r] = (part == 1) ? (__bf16)(wv - (float)wh) : wh;
            }
            whh_hi[kk] = hi;
            whh_lo[kk] = lo;
            wih[kk]    = xa;
        }
    }

    const int u_c = 4 * w + q;                    // this lane's hidden unit
    float bias4[4];
#pragma unroll
    for (int r = 0; r < 4; ++r) bias4[r] = bih[r * 64 + u_c] + bhh[r * 64 + u_c];

    // precomputed LDS pointers (ELEMENT offsets; dbuf stride: hbuf 2048, xbuf 1024)
    __bf16* const hw_base = &hbuf[0][0][0][0][0] +
                            ((u_c >> 3) * 128 + bb * 8 + (u_c & 7)); // +part*1024
    const __bf16* const hr_base = &hbuf[0][0][0][0][0] + 8 * (size_t)l;
    const __bf16* const xr_base = &xbuf[0][0][0][0] + 8 * (size_t)l;

    __syncthreads();

    float cst = 0.0f;

#pragma unroll 4
    for (int t = 0; t < T_SEQ; ++t) {
        const int cur = t & 1;
        const int nxt = cur ^ 1;
        const int s   = t & 3;

        // B-fragments: lane l reads contiguous 16B at element 8*l -- conflict-free
        const __bf16* hr = hr_base + cur * 2048;
        const __bf16* xr = xr_base + cur * 1024;
        const bf16x8 bx0 = *reinterpret_cast<const bf16x8*>(xr);          // chunks 0-3
        const bf16x8 bx1 = *reinterpret_cast<const bf16x8*>(xr + 512);    // chunks 4-7
        const bf16x8 bh0 = *reinterpret_cast<const bf16x8*>(hr);          // hi, 0-3
        const bf16x8 bh1 = *reinterpret_cast<const bf16x8*>(hr + 512);    // hi, 4-7
        const bf16x8 bl0 = *reinterpret_cast<const bf16x8*>(hr + 1024);   // lo, 0-3
        const bf16x8 bl1 = *reinterpret_cast<const bf16x8*>(hr + 1536);   // lo, 4-7

        // write x(t+1) from the prefetch queue (value already in register --
        // no vmcnt stall here), then refill the slot with x(t+5)
        {
            const float vs = xq[s];
            const __bf16 sh = (__bf16)vs;
            xbase[nxt * 1024 + tid] = (part_s == 1) ? (__bf16)(vs - (float)sh) : sh;
        }
        {
            const int tload = (t + 5 < T_SEQ) ? (t + 5) : (T_SEQ - 1);
            xq[s] = (part_s == 2) ? 0.0f : xsrc[tload * F_IN];
        }

        // four independent 2-deep MFMA chains
        f32x4 acc_a = {bias4[0], bias4[1], bias4[2], bias4[3]};
        f32x4 acc_b = {0.0f, 0.0f, 0.0f, 0.0f};
        f32x4 acc_c = {0.0f, 0.0f, 0.0f, 0.0f};
        f32x4 acc_d = {0.0f, 0.0f, 0.0f, 0.0f};
        acc_a = __builtin_amdgcn_mfma_f32_16x16x32_bf16(wih[0],    bx0, acc_a, 0, 0, 0);
        acc_b = __builtin_amdgcn_mfma_f32_16x16x32_bf16(wih[1],    bx1, acc_b, 0, 0, 0);
        acc_c = __builtin_amdgcn_mfma_f32_16x16x32_bf16(whh_lo[0], bh0, acc_c, 0, 0, 0);
        acc_d = __builtin_amdgcn_mfma_f32_16x16x32_bf16(whh_lo[1], bh1, acc_d, 0, 0, 0);
        acc_a = __builtin_amdgcn_mfma_f32_16x16x32_bf16(whh_hi[0], bh0, acc_a, 0, 0, 0);
        acc_b = __builtin_amdgcn_mfma_f32_16x16x32_bf16(whh_hi[1], bh1, acc_b, 0, 0, 0);
        acc_c = __builtin_amdgcn_mfma_f32_16x16x32_bf16(whh_hi[0], bl0, acc_c, 0, 0, 0);
        acc_d = __builtin_amdgcn_mfma_f32_16x16x32_bf16(whh_hi[1], bl1, acc_d, 0, 0, 0);

        const f32x4 acc = (acc_a + acc_b) + (acc_c + acc_d);

        // lane-local cell update: acc[r] = gate {i,f,g,o} of (bb, u_c)
        const float gi = sigm(acc[0]);
        const float gf = sigm(acc[1]);
        const float gg = tanh_fast(acc[2]);
        const float go = sigm(acc[3]);
        const float c  = gf * cst + gi * gg;
        cst = c;
        const float h  = go * tanh_fast(c);
        const __bf16 hh = (__bf16)h;
        const __bf16 hl = (__bf16)(h - (float)hh);
        __bf16* hw = hw_base + nxt * 2048;
        hw[0]    = hh;
        hw[1024] = hl;
        if (t == T_SEQ - 1) h32[bb][u_c] = h;

        BARRIER_LDS();
    }

    // ---- classifier epilogue: out[b][o] = h . Wcls[o] + bcls[o] ----
    if (tid < NB * NO) {
        const int bo = tid / NO;
        const int o  = tid % NO;
        float ssum = bcls[o];
#pragma unroll 8
        for (int k = 0; k < HID; ++k)
            ssum += h32[bo][k] * Wcls[o * HID + k];
        out[(long)(b0 + bo) * NO + o] = ssum;
    }
}

extern "C" void kernel_launch(void* const* d_in, const int* in_sizes, int n_in,
                              void* d_out, int out_size, void* d_ws, size_t ws_size,
                              hipStream_t stream)
{
    const float* X    = (const float*)d_in[0];
    const float* Wih  = (const float*)d_in[1];
    const float* Whh  = (const float*)d_in[2];
    const float* bih  = (const float*)d_in[3];
    const float* bhh  = (const float*)d_in[4];
    const float* Wcls = (const float*)d_in[5];
    const float* bcls = (const float*)d_in[6];
    float* outp = (float*)d_out;

    dim3 grid(4096 / NB);   // 256 blocks -> 1 per CU
    dim3 block(1024);       // 16 waves -> 4 waves/SIMD
    lstm_fused<<<grid, block, 0, stream>>>(X, Wih, Whh, bih, bhh, Wcls, bcls, outp);
}

// Round 12
// 254.673 us; speedup vs baseline: 1.3118x; 1.1104x over previous
//
#include <hip/hip_runtime.h>
#include <hip/hip_bf16.h>

typedef __attribute__((ext_vector_type(8))) __bf16 bf16x8;
typedef __attribute__((ext_vector_type(4))) float  f32x4;

#define T_SEQ 256
#define F_IN  18
#define HID   64
#define NB    16
#define NO    15

static __device__ __forceinline__ float rcp_fast(float x) {
    return __builtin_amdgcn_rcpf(x);
}
static __device__ __forceinline__ float sigm(float x) {
    return rcp_fast(1.0f + __expf(-x));
}
static __device__ __forceinline__ float tanh_fast(float x) {
    return 1.0f - 2.0f * rcp_fast(__expf(2.0f * x) + 1.0f);
}

// LDS-only barrier: no vmcnt(0) drain, thread-private global prefetch loads
// stay in flight across it.
#define BARRIER_LDS() asm volatile("s_waitcnt lgkmcnt(0)\n\ts_barrier" ::: "memory")

// 256 blocks x 1024 threads (16 waves), 16 batches/block, 1 cell/lane.
// Wave w owns gate-row tile T=w (perm rows p=4u+g -> units u=4w..4w+3).
// Lane: bb=l&15, q=l>>4; C layout col=bb, row=4q+r -> u=4w+q, gate g=r.
//
// R12: h kept as bf16 ONLY (h_lo split-term dropped -- accuracy analysis:
// ~4e-4/step pre-act error, damped random walk -> est 2-4e-3 output absmax
// vs 6.5e-3 threshold). x keeps the hi/lo 3-product packing (free: fits the
// same 2 MFMAs).
//   B packed K: [x_hi(18)|x_hi(18)|x_lo(18)|0(10)] + h_hi(64) read twice
//   A packed K: [Wih_hi  |Wih_lo  |Wih_hi  |0    ] ; Whh_hi(64); Whh_lo(64)
//   6 MFMAs as 3 independent 2-deep chains; acc = (a+b)+c.
// LDS: hbuf[dbuf][chunk8][bb16][8] -- lane l reads element 8*l (contiguous
// 1024B/wave, conflict-free); single bf16 h write per lane per step.
__global__ __launch_bounds__(1024, 4) void lstm_fused(
    const float* __restrict__ X,
    const float* __restrict__ Wih,
    const float* __restrict__ Whh,
    const float* __restrict__ bih,
    const float* __restrict__ bhh,
    const float* __restrict__ Wcls,
    const float* __restrict__ bcls,
    float* __restrict__ out)
{
    const int tid = threadIdx.x;
    const int l   = tid & 63;
    const int w   = tid >> 6;
    const int q   = l >> 4;
    const int bb  = l & 15;
    const int b0  = blockIdx.x * NB;

    __shared__ __align__(16) __bf16 hbuf[2][8][NB][8];   // h_hi only
    __shared__ __align__(16) __bf16 xbuf[2][8][NB][8];
    __shared__ float h32[NB][HID];

    // ---- x staging map: thread tid stages packed element linear==tid ----
    const int sb = (tid >> 3) & 15;                    // batch
    const int sk = ((tid >> 7) << 3) | (tid & 7);      // packed k
    int f_s, part_s;                                   // 0=hi, 1=lo, 2=zero
    if (sk < 18)      { f_s = sk;      part_s = 0; }
    else if (sk < 36) { f_s = sk - 18; part_s = 0; }
    else if (sk < 54) { f_s = sk - 36; part_s = 1; }
    else              { f_s = 0;       part_s = 2; }
    const float* xsrc = X + ((long)(b0 + sb) * T_SEQ) * F_IN + f_s;
    __bf16* const xbase = &xbuf[0][0][0][0];           // + dbuf*1024 + tid

    // ---- zero initial h (dbuf0; dbuf1 fully written at t=0) ----
    {
        __bf16* hz = &hbuf[0][0][0][0];
        for (int i = tid; i < 8 * NB * 8; i += 1024) hz[i] = (__bf16)0.0f;
    }
    // ---- stage x(0); fill 4-deep prefetch queue with x(1..4) ----
    {
        const float v = (part_s == 2) ? 0.0f : xsrc[0];
        const __bf16 hi = (__bf16)v;
        xbase[tid] = (part_s == 1) ? (__bf16)(v - (float)hi) : hi;
    }
    float xq[4];
#pragma unroll
    for (int i = 0; i < 4; ++i)
        xq[i] = (part_s == 2) ? 0.0f : xsrc[(1 + i) * F_IN];

    // ---- constant A-fragments ----
    bf16x8 whh_hi[2], whh_lo[2], wih[2];
    {
        const int prow = 16 * w + bb;
        const int jrow = (prow & 3) * 64 + (prow >> 2);
#pragma unroll
        for (int kk = 0; kk < 2; ++kk) {
            bf16x8 hi, lo, xa;
#pragma unroll
            for (int r = 0; r < 8; ++r) {
                const int k = 32 * kk + 8 * q + r;
                const float v = Whh[jrow * HID + k];
                const __bf16 vh = (__bf16)v;
                hi[r] = vh;
                lo[r] = (__bf16)(v - (float)vh);
                int f, part;
                if (k < 18)      { f = k;      part = 0; }
                else if (k < 36) { f = k - 18; part = 1; }
                else if (k < 54) { f = k - 36; part = 0; }
                else             { f = 0;      part = 2; }
                const float wv = (part == 2) ? 0.0f : Wih[jrow * F_IN + f];
                const __bf16 wh = (__bf16)wv;
                xa[r] = (part == 1) ? (__bf16)(wv - (float)wh) : wh;
            }
            whh_hi[kk] = hi;
            whh_lo[kk] = lo;
            wih[kk]    = xa;
        }
    }

    const int u_c = 4 * w + q;
    float bias4[4];
#pragma unroll
    for (int r = 0; r < 4; ++r) bias4[r] = bih[r * 64 + u_c] + bhh[r * 64 + u_c];

    // LDS pointers (ELEMENT offsets; dbuf stride 1024 for both bufs)
    __bf16* const hw_base = &hbuf[0][0][0][0] +
                            ((u_c >> 3) * 128 + bb * 8 + (u_c & 7));
    const __bf16* const hr_base = &hbuf[0][0][0][0] + 8 * (size_t)l;
    const __bf16* const xr_base = &xbuf[0][0][0][0] + 8 * (size_t)l;

    __syncthreads();

    float cst = 0.0f;

    // One timestep. PF: 0=unclamped prefetch of t+5, 1=clamped; LAST: write h32.
#define STEP(t_, PF, LAST)                                                          \
    {                                                                               \
        const int cur_ = (t_) & 1;                                                  \
        const int nxt_ = cur_ ^ 1;                                                  \
        const int s_   = (t_) & 3;                                                  \
        const __bf16* hr = hr_base + cur_ * 1024;                                   \
        const __bf16* xr = xr_base + cur_ * 1024;                                   \
        const bf16x8 bx0 = *reinterpret_cast<const bf16x8*>(xr);                    \
        const bf16x8 bx1 = *reinterpret_cast<const bf16x8*>(xr + 512);              \
        const bf16x8 bh0 = *reinterpret_cast<const bf16x8*>(hr);                    \
        const bf16x8 bh1 = *reinterpret_cast<const bf16x8*>(hr + 512);              \
        {                                                                           \
            const float vs = xq[s_];                                                \
            const __bf16 sh = (__bf16)vs;                                           \
            xbase[nxt_ * 1024 + tid] = (part_s == 1) ? (__bf16)(vs - (float)sh) : sh; \
        }                                                                           \
        {                                                                           \
            const int tl_ = PF ? (((t_) + 5 < T_SEQ) ? (t_) + 5 : (T_SEQ - 1))      \
                               : ((t_) + 5);                                        \
            xq[s_] = (part_s == 2) ? 0.0f : xsrc[tl_ * F_IN];                       \
        }                                                                           \
        __builtin_amdgcn_s_setprio(1);                                              \
        f32x4 acc_a = {bias4[0], bias4[1], bias4[2], bias4[3]};                     \
        f32x4 acc_b = {0.0f, 0.0f, 0.0f, 0.0f};                                     \
        f32x4 acc_c = {0.0f, 0.0f, 0.0f, 0.0f};                                     \
        acc_a = __builtin_amdgcn_mfma_f32_16x16x32_bf16(wih[0],    bx0, acc_a, 0, 0, 0); \
        acc_b = __builtin_amdgcn_mfma_f32_16x16x32_bf16(wih[1],    bx1, acc_b, 0, 0, 0); \
        acc_c = __builtin_amdgcn_mfma_f32_16x16x32_bf16(whh_lo[0], bh0, acc_c, 0, 0, 0); \
        acc_a = __builtin_amdgcn_mfma_f32_16x16x32_bf16(whh_hi[0], bh0, acc_a, 0, 0, 0); \
        acc_b = __builtin_amdgcn_mfma_f32_16x16x32_bf16(whh_hi[1], bh1, acc_b, 0, 0, 0); \
        acc_c = __builtin_amdgcn_mfma_f32_16x16x32_bf16(whh_lo[1], bh1, acc_c, 0, 0, 0); \
        const f32x4 acc = (acc_a + acc_b) + acc_c;                                  \
        const float gi = sigm(acc[0]);                                              \
        const float gf = sigm(acc[1]);                                              \
        const float gg = tanh_fast(acc[2]);                                         \
        const float go = sigm(acc[3]);                                              \
        const float c  = gf * cst + gi * gg;                                        \
        cst = c;                                                                    \
        const float h  = go * tanh_fast(c);                                         \
        hw_base[nxt_ * 1024] = (__bf16)h;                                           \
        __builtin_amdgcn_s_setprio(0);                                              \
        if (LAST) h32[bb][u_c] = h;                                                 \
        BARRIER_LDS();                                                              \
    }

    // main loop: t in [0,248), prefetch t+5 <= 252 needs no clamp
#pragma unroll 4
    for (int t = 0; t < 248; ++t) {
        STEP(t, 0, 0)
    }
    // tail: fully unrolled (static xq index), clamped prefetch
#pragma unroll
    for (int tt = 248; tt < T_SEQ; ++tt) {
        STEP(tt, 1, (tt == T_SEQ - 1))
    }
#undef STEP

    // ---- classifier epilogue ----
    if (tid < NB * NO) {
        const int bo = tid / NO;
        const int o  = tid % NO;
        float ssum = bcls[o];
#pragma unroll 8
        for (int k = 0; k < HID; ++k)
            ssum += h32[bo][k] * Wcls[o * HID + k];
        out[(long)(b0 + bo) * NO + o] = ssum;
    }
}

extern "C" void kernel_launch(void* const* d_in, const int* in_sizes, int n_in,
                              void* d_out, int out_size, void* d_ws, size_t ws_size,
                              hipStream_t stream)
{
    const float* X    = (const float*)d_in[0];
    const float* Wih  = (const float*)d_in[1];
    const float* Whh  = (const float*)d_in[2];
    const float* bih  = (const float*)d_in[3];
    const float* bhh  = (const float*)d_in[4];
    const float* Wcls = (const float*)d_in[5];
    const float* bcls = (const float*)d_in[6];
    float* outp = (float*)d_out;

    dim3 grid(4096 / NB);   // 256 blocks -> 1 per CU
    dim3 block(1024);       // 16 waves -> 4 waves/SIMD
    lstm_fused<<<grid, block, 0, stream>>>(X, Wih, Whh, bih, bhh, Wcls, bcls, outp);
}

// Round 15
// 233.590 us; speedup vs baseline: 1.4302x; 1.0903x over previous
//
#include <hip/hip_runtime.h>
#include <hip/hip_bf16.h>

typedef __attribute__((ext_vector_type(8))) __bf16 bf16x8;
typedef __attribute__((ext_vector_type(4))) float  f32x4;

#define T_SEQ 256
#define F_IN  18
#define HID   64
#define NB    16
#define NO    15

static __device__ __forceinline__ float rcp_fast(float x) {
    return __builtin_amdgcn_rcpf(x);
}
static __device__ __forceinline__ float sigm(float x) {
    return rcp_fast(1.0f + __expf(-x));
}
static __device__ __forceinline__ float tanh_fast(float x) {
    return 1.0f - 2.0f * rcp_fast(__expf(2.0f * x) + 1.0f);
}

// LDS-only barrier: no vmcnt(0) drain; thread-private global prefetch loads
// stay in flight across it.
#define BARRIER_LDS() asm volatile("s_waitcnt lgkmcnt(0)\n\ts_barrier" ::: "memory")

// 256 blocks x 1024 threads (16 waves), 16 batches/block, 1 cell/lane.
// Wave w owns gate-row tile T=w (perm rows p=4u+g -> units u=4w..4w+3).
// Lane: bb=l&15, q=l>>4; C layout col=bb, row=4q+r -> u=4w+q, gate g=r.
//
// R13: UNIFIED K=128 B-stream, 4 MFMAs/step (was 6):
//   B slots: [0,18)=x_hi[f=k]  [18,36)=x_hi[f=k-18]  [36,100)=h[u=k-36]
//            [100,128)=0
//   A slots: [Wih_hi | Wih_lo | Whh_hi | 0]
// Dropped terms (each ~2^-9-scale, mirror of the h_lo term R12 proved has
// ZERO effect at the bf16 output floor): Whh_lo*h and Wih_hi*x_lo.
// MFMA j uses slots [32j,32j+32); lane reads B fragment j at element
// 512*j + 8*l (contiguous 1024B/wave, conflict-free). Unified buffer:
// ubuf[dbuf][chunk16][bb16][idx8], element linear = chunk*128+bb*8+idx,
// slot k -> chunk=k>>3, idx=k&7.
__global__ __launch_bounds__(1024, 4) void lstm_fused(
    const float* __restrict__ X,
    const float* __restrict__ Wih,
    const float* __restrict__ Whh,
    const float* __restrict__ bih,
    const float* __restrict__ bhh,
    const float* __restrict__ Wcls,
    const float* __restrict__ bcls,
    float* __restrict__ out)
{
    const int tid = threadIdx.x;
    const int l   = tid & 63;
    const int w   = tid >> 6;
    const int q   = l >> 4;
    const int bb  = l & 15;
    const int b0  = blockIdx.x * NB;

    __shared__ __align__(16) __bf16 ubuf[2][16][NB][8];   // 2 x 2048 elements
    __shared__ float h32[NB][HID];

    // ---- x staging map: element linear == tid for tid<640 with slot<36 ----
    const int sk = ((tid >> 7) << 3) | (tid & 7);      // k slot if tid<640
    const int sb = (tid >> 3) & 15;                    // batch
    const bool stager = (tid < 640) && (sk < 36);
    const int f_s = (sk < 18) ? sk : (sk - 18);
    const float* xsrc = X + ((long)(b0 + sb) * T_SEQ) * F_IN + f_s;
    __bf16* const ubase = &ubuf[0][0][0][0];           // + dbuf*2048

    // ---- zero both dbufs (h(0)=0; pad slots [100,128) stay 0 forever) ----
    for (int i = tid; i < 2 * 16 * NB * 8; i += 1024) ubase[i] = (__bf16)0.0f;

    // ---- stage x(0); fill 4-deep prefetch queue with x(1..4) ----
    if (stager) ubase[tid] = (__bf16)xsrc[0];
    float xq[4];
#pragma unroll
    for (int i = 0; i < 4; ++i)
        xq[i] = stager ? xsrc[(1 + i) * F_IN] : 0.0f;

    // ---- constant A-fragments (4 x bf16x8, live whole kernel) ----
    bf16x8 afrag[4];
    {
        const int prow = 16 * w + bb;                   // permuted gate row
        const int jrow = (prow & 3) * 64 + (prow >> 2); // original row g*64+u
#pragma unroll
        for (int j = 0; j < 4; ++j) {
            bf16x8 v;
#pragma unroll
            for (int r = 0; r < 8; ++r) {
                const int k = 32 * j + 8 * q + r;
                float val;
                if (k < 18) {
                    val = Wih[jrow * F_IN + k];                    // Wih_hi
                } else if (k < 36) {
                    const float wv = Wih[jrow * F_IN + (k - 18)];  // Wih_lo
                    val = wv - (float)((__bf16)wv);
                } else if (k < 100) {
                    val = Whh[jrow * HID + (k - 36)];              // Whh_hi
                } else {
                    val = 0.0f;
                }
                v[r] = (__bf16)val;
            }
            afrag[j] = v;
        }
    }

    const int u_c = 4 * w + q;
    float bias4[4];
#pragma unroll
    for (int r = 0; r < 4; ++r) bias4[r] = bih[r * 64 + u_c] + bhh[r * 64 + u_c];

    // LDS pointers (ELEMENT offsets; dbuf stride 2048)
    const int hslot = 36 + u_c;
    __bf16* const hw_base = ubase + ((hslot >> 3) * 128 + bb * 8 + (hslot & 7));
    const __bf16* const rd_base = ubase + 8 * (size_t)l;

    __syncthreads();

    float cst = 0.0f;

    // One timestep. PF: 0=unclamped prefetch of t+5, 1=clamped; LAST: write h32.
#define STEP(t_, PF, LAST)                                                          \
    {                                                                               \
        const int cur_ = (t_) & 1;                                                  \
        const int nxt_ = cur_ ^ 1;                                                  \
        const int s_   = (t_) & 3;                                                  \
        const __bf16* rp = rd_base + cur_ * 2048;                                   \
        const bf16x8 bf0 = *reinterpret_cast<const bf16x8*>(rp);                    \
        const bf16x8 bf1 = *reinterpret_cast<const bf16x8*>(rp + 512);              \
        const bf16x8 bf2 = *reinterpret_cast<const bf16x8*>(rp + 1024);             \
        const bf16x8 bf3 = *reinterpret_cast<const bf16x8*>(rp + 1536);             \
        if (stager) {                                                               \
            ubase[nxt_ * 2048 + tid] = (__bf16)xq[s_];                              \
            const int tl_ = PF ? (((t_) + 5 < T_SEQ) ? (t_) + 5 : (T_SEQ - 1))      \
                               : ((t_) + 5);                                        \
            xq[s_] = xsrc[tl_ * F_IN];                                              \
        }                                                                           \
        __builtin_amdgcn_s_setprio(1);                                              \
        f32x4 acc_a = {bias4[0], bias4[1], bias4[2], bias4[3]};                     \
        f32x4 acc_b = {0.0f, 0.0f, 0.0f, 0.0f};                                     \
        acc_a = __builtin_amdgcn_mfma_f32_16x16x32_bf16(afrag[0], bf0, acc_a, 0, 0, 0); \
        acc_b = __builtin_amdgcn_mfma_f32_16x16x32_bf16(afrag[1], bf1, acc_b, 0, 0, 0); \
        acc_a = __builtin_amdgcn_mfma_f32_16x16x32_bf16(afrag[2], bf2, acc_a, 0, 0, 0); \
        acc_b = __builtin_amdgcn_mfma_f32_16x16x32_bf16(afrag[3], bf3, acc_b, 0, 0, 0); \
        const f32x4 acc = acc_a + acc_b;                                            \
        const float gi = sigm(acc[0]);                                              \
        const float gf = sigm(acc[1]);                                              \
        const float gg = tanh_fast(acc[2]);                                         \
        const float go = sigm(acc[3]);                                              \
        const float c  = gf * cst + gi * gg;                                        \
        cst = c;                                                                    \
        const float h  = go * tanh_fast(c);                                         \
        hw_base[nxt_ * 2048] = (__bf16)h;                                           \
        __builtin_amdgcn_s_setprio(0);                                              \
        if (LAST) h32[bb][u_c] = h;                                                 \
        BARRIER_LDS();                                                              \
    }

    // main loop: t in [0,248), prefetch t+5 <= 252 needs no clamp
#pragma unroll 4
    for (int t = 0; t < 248; ++t) {
        STEP(t, 0, 0)
    }
    // tail: fully unrolled (static xq index), clamped prefetch
#pragma unroll
    for (int tt = 248; tt < T_SEQ; ++tt) {
        STEP(tt, 1, (tt == T_SEQ - 1))
    }
#undef STEP

    // ---- classifier epilogue: out[b][o] = h . Wcls[o] + bcls[o] ----
    if (tid < NB * NO) {
        const int bo = tid / NO;
        const int o  = tid % NO;
        float ssum = bcls[o];
#pragma unroll 8
        for (int k = 0; k < HID; ++k)
            ssum += h32[bo][k] * Wcls[o * HID + k];
        out[(long)(b0 + bo) * NO + o] = ssum;
    }
}

extern "C" void kernel_launch(void* const* d_in, const int* in_sizes, int n_in,
                              void* d_out, int out_size, void* d_ws, size_t ws_size,
                              hipStream_t stream)
{
    const float* X    = (const float*)d_in[0];
    const float* Wih  = (const float*)d_in[1];
    const float* Whh  = (const float*)d_in[2];
    const float* bih  = (const float*)d_in[3];
    const float* bhh  = (const float*)d_in[4];
    const float* Wcls = (const float*)d_in[5];
    const float* bcls = (const float*)d_in[6];
    float* outp = (float*)d_out;

    dim3 grid(4096 / NB);   // 256 blocks -> 1 per CU
    dim3 block(1024);       // 16 waves -> 4 waves/SIMD
    lstm_fused<<<grid, block, 0, stream>>>(X, Wih, Whh, bih, bhh, Wcls, bcls, outp);
}